// Round 2
// baseline (755.559 us; speedup 1.0000x reference)
//
#include <hip/hip_runtime.h>

#define NNODES 50000
#define NEDGES 1600000
#define FEAT   128
#define EPSV   1e-5f

// ---------------- sum of all x (for mean) ----------------
__global__ __launch_bounds__(256) void sum_kernel(const float* __restrict__ x,
                                                  float* __restrict__ out, int n4) {
  const float4* x4 = (const float4*)x;
  float s = 0.f;
  for (int i = blockIdx.x * blockDim.x + threadIdx.x; i < n4; i += gridDim.x * blockDim.x) {
    float4 v = x4[i];
    s += v.x + v.y + v.z + v.w;
  }
  for (int off = 32; off > 0; off >>= 1) s += __shfl_down(s, off);
  __shared__ float ls[4];
  int wid = threadIdx.x >> 6;
  if ((threadIdx.x & 63) == 0) ls[wid] = s;
  __syncthreads();
  if (threadIdx.x == 0) atomicAdd(out, ls[0] + ls[1] + ls[2] + ls[3]);
}

// ---------------- xn = x + noise * mean(x) ----------------
__global__ __launch_bounds__(256) void noisy_kernel(const float* __restrict__ x,
                                                    const float* __restrict__ noise,
                                                    const float* __restrict__ sumv,
                                                    float* __restrict__ xn, int n4) {
  int i = blockIdx.x * blockDim.x + threadIdx.x;
  if (i >= n4) return;
  float mean = *sumv * (1.0f / (float)(NNODES * FEAT));
  float4 a = ((const float4*)x)[i];
  float4 b = ((const float4*)noise)[i];
  float4 o;
  o.x = a.x + b.x * mean; o.y = a.y + b.y * mean;
  o.z = a.z + b.z * mean; o.w = a.w + b.w * mean;
  ((float4*)xn)[i] = o;
}

// ---------------- degree over dst ----------------
__global__ __launch_bounds__(256) void degree_kernel(const int* __restrict__ ei,
                                                     int* __restrict__ degi, int ne) {
  int e = blockIdx.x * blockDim.x + threadIdx.x;
  if (e < ne) atomicAdd(&degi[ei[NEDGES + e]], 1);
}

__global__ __launch_bounds__(256) void dinv_kernel(const int* __restrict__ degi,
                                                   float* __restrict__ dinv, int n) {
  int i = blockIdx.x * blockDim.x + threadIdx.x;
  if (i < n) dinv[i] = (degi[i] > 0) ? rsqrtf((float)degi[i]) : 0.f;
}

// ---------------- exclusive scan (3-kernel, N=50000) ----------------
__global__ __launch_bounds__(1024) void scan1_kernel(const int* __restrict__ cnt,
                                                     int* __restrict__ exc,
                                                     int* __restrict__ bsum, int n) {
  __shared__ int s[1024];
  int tid = threadIdx.x;
  int i = blockIdx.x * 1024 + tid;
  int v = (i < n) ? cnt[i] : 0;
  int val = v;
  s[tid] = v;
  __syncthreads();
  for (int off = 1; off < 1024; off <<= 1) {
    int t = (tid >= off) ? s[tid - off] : 0;
    __syncthreads();
    val += t;
    s[tid] = val;
    __syncthreads();
  }
  if (i < n) exc[i] = val - v;          // exclusive, without block offset
  if (tid == 1023) bsum[blockIdx.x] = val;
}

__global__ __launch_bounds__(256) void scan2_kernel(int* __restrict__ bsum, int nb) {
  __shared__ int s[256];
  int tid = threadIdx.x;
  int v = (tid < nb) ? bsum[tid] : 0;
  int val = v;
  s[tid] = v;
  __syncthreads();
  for (int off = 1; off < 256; off <<= 1) {
    int t = (tid >= off) ? s[tid - off] : 0;
    __syncthreads();
    val += t;
    s[tid] = val;
    __syncthreads();
  }
  if (tid < nb) bsum[tid] = val - v;    // exclusive block offsets
}

__global__ __launch_bounds__(256) void scan3_kernel(int* __restrict__ row_ptr,
                                                    const int* __restrict__ bsum,
                                                    int* __restrict__ cursor, int n) {
  int i = blockIdx.x * blockDim.x + threadIdx.x;
  if (i < n) {
    int v = row_ptr[i] + bsum[i >> 10];
    row_ptr[i] = v;
    cursor[i] = v;
  } else if (i == n) {
    row_ptr[n] = NEDGES;
  }
}

// ---------------- CSR fill: epacked[pos] = (src, w_e) ----------------
__global__ __launch_bounds__(256) void csr_fill_kernel(const int* __restrict__ ei,
                                                       const float* __restrict__ dinv,
                                                       int* __restrict__ cursor,
                                                       int2* __restrict__ ep, int ne) {
  int e = blockIdx.x * blockDim.x + threadIdx.x;
  if (e >= ne) return;
  int s = ei[e];
  int d = ei[NEDGES + e];
  float w = dinv[s] * dinv[d];
  int pos = atomicAdd(&cursor[d], 1);
  ep[pos] = make_int2(s, __float_as_int(w));
}

// ---------------- dense GEMM: out = [A1|A2] @ [W0;W1] (+bias) ----------------
// ROWCAT: K-concat (A1 K/2 cols, A2 K/2 cols; W0/W1 are (K/2 x NOUT))
// !ROWCAT: col-concat (A1 has K cols; W0/W1 are (K x NOUT/2); out = [A1@W0 | A1@W1])
template <int K, int NOUT, bool ROWCAT, bool BIAS>
__global__ __launch_bounds__(256) void gemm_kernel(const float* __restrict__ A1,
                                                   const float* __restrict__ A2,
                                                   const float* __restrict__ W0,
                                                   const float* __restrict__ W1,
                                                   const float* __restrict__ bias,
                                                   float* __restrict__ out, int n) {
  constexpr int TC  = NOUT / 4;        // threads per row
  constexpr int RG  = 256 / TC;        // row-groups per block
  constexpr int RPT = 4;               // rows per thread
  constexpr int RPB = RG * RPT;        // rows per block
  constexpr int AP  = (K == 128) ? K : (K + 1);  // pad to avoid LDS bank conflicts
  __shared__ float wl[K * NOUT];
  __shared__ float al[RPB * AP];
  const int tid = threadIdx.x;

  for (int i = tid; i < K * NOUT; i += 256) {
    int k = i / NOUT, j = i - k * NOUT;
    float v;
    if (ROWCAT) v = (k < K / 2) ? W0[k * NOUT + j] : W1[(k - K / 2) * NOUT + j];
    else        v = (j < NOUT / 2) ? W0[k * (NOUT / 2) + j] : W1[k * (NOUT / 2) + (j - NOUT / 2)];
    wl[i] = v;
  }
  const int row0 = blockIdx.x * RPB;
  for (int i = tid; i < RPB * K; i += 256) {
    int r = i / K, k = i - r * K;
    int gr = row0 + r;
    float v = 0.f;
    if (gr < n) {
      if (ROWCAT) v = (k < K / 2) ? A1[gr * (K / 2) + k] : A2[gr * (K / 2) + (k - K / 2)];
      else        v = A1[gr * K + k];
    }
    al[r * AP + k] = v;
  }
  __syncthreads();

  const int jt = (tid % TC) * 4;
  const int rbase = (tid / TC) * RPT;
  float acc[RPT][4] = {};
#pragma unroll 4
  for (int k = 0; k < K; ++k) {
    float4 w4 = *(const float4*)&wl[k * NOUT + jt];
#pragma unroll
    for (int rr = 0; rr < RPT; ++rr) {
      float a = al[(rbase + rr) * AP + k];
      acc[rr][0] = fmaf(a, w4.x, acc[rr][0]);
      acc[rr][1] = fmaf(a, w4.y, acc[rr][1]);
      acc[rr][2] = fmaf(a, w4.z, acc[rr][2]);
      acc[rr][3] = fmaf(a, w4.w, acc[rr][3]);
    }
  }
  float4 b4 = make_float4(0.f, 0.f, 0.f, 0.f);
  if (BIAS) b4 = *(const float4*)&bias[jt];
#pragma unroll
  for (int rr = 0; rr < RPT; ++rr) {
    int gr = row0 + rbase + rr;
    if (gr < n) {
      float4 o;
      o.x = acc[rr][0] + b4.x; o.y = acc[rr][1] + b4.y;
      o.z = acc[rr][2] + b4.z; o.w = acc[rr][3] + b4.w;
      *(float4*)&out[gr * NOUT + jt] = o;
    }
  }
}

// ---------------- CSR SpMM: out[n][f] = (ADD? mat[n*S+f]+bias[f] : 0) - sum_e w*mat[src*S+OFF+f]
template <int F, bool ADD>
__global__ __launch_bounds__(256) void spmm_kernel(const int* __restrict__ row_ptr,
                                                   const int2* __restrict__ ep,
                                                   const float* __restrict__ mat, int S, int OFF,
                                                   const float* __restrict__ bias,
                                                   float* __restrict__ out, int n) {
  constexpr int GP = 256 / F;
  const int f = threadIdx.x & (F - 1);
  const int g = threadIdx.x / F;
  const int node = blockIdx.x * GP + g;
  if (node >= n) return;
  const int beg = row_ptr[node];
  const int end = row_ptr[node + 1];
  float acc = 0.f;
  int e = beg;
  for (; e + 1 < end; e += 2) {
    int2 sw0 = ep[e];
    int2 sw1 = ep[e + 1];
    acc -= __int_as_float(sw0.y) * mat[sw0.x * S + OFF + f];
    acc -= __int_as_float(sw1.y) * mat[sw1.x * S + OFF + f];
  }
  if (e < end) {
    int2 sw = ep[e];
    acc -= __int_as_float(sw.y) * mat[sw.x * S + OFF + f];
  }
  float r = acc;
  if (ADD) r += mat[node * S + f] + bias[f];
  out[node * F + f] = r;
}

// ---------------- BN stats: stats[0:F]=sum, stats[F:2F]=sumsq ----------------
template <int F>
__global__ __launch_bounds__(256) void bn_stats_kernel(const float* __restrict__ z,
                                                       float* __restrict__ stats, int n) {
  __shared__ float s[2 * F];
  if (threadIdx.x < 2 * F) s[threadIdx.x] = 0.f;
  __syncthreads();
  constexpr int GP = 256 / F;
  const int f = threadIdx.x & (F - 1);
  const int g = threadIdx.x / F;
  float sum = 0.f, sq = 0.f;
  for (int r = blockIdx.x * GP + g; r < n; r += gridDim.x * GP) {
    float v = z[r * F + f];
    sum += v;
    sq += v * v;
  }
  atomicAdd(&s[f], sum);
  atomicAdd(&s[F + f], sq);
  __syncthreads();
  if (threadIdx.x < 2 * F) atomicAdd(&stats[threadIdx.x], s[threadIdx.x]);
}

// ---------------- BN apply + ReLU (in place) ----------------
template <int F>
__global__ __launch_bounds__(256) void bn_apply_kernel(float* __restrict__ z,
                                                       const float* __restrict__ stats,
                                                       const float* __restrict__ gw,
                                                       const float* __restrict__ be, int n) {
  const int idx = blockIdx.x * blockDim.x + threadIdx.x;
  if (idx >= n * F) return;
  const int f = idx & (F - 1);
  const float inv_n = 1.0f / (float)n;
  float mu = stats[f] * inv_n;
  float var = stats[F + f] * inv_n - mu * mu;
  float v = (z[idx] - mu) * rsqrtf(var + EPSV) * gw[f] + be[f];
  z[idx] = fmaxf(v, 0.f);
}

extern "C" void kernel_launch(void* const* d_in, const int* in_sizes, int n_in,
                              void* d_out, int out_size, void* d_ws, size_t ws_size,
                              hipStream_t stream) {
  const float* x     = (const float*)d_in[0];
  const float* noise = (const float*)d_in[1];
  const int*   ei    = (const int*)d_in[2];   // int32! harness casts integer inputs to int32
  const float* W1_0 = (const float*)d_in[3];
  const float* W1_1 = (const float*)d_in[4];
  const float* b1   = (const float*)d_in[5];
  const float* g1   = (const float*)d_in[6];
  const float* be1  = (const float*)d_in[7];
  const float* W2_0 = (const float*)d_in[8];
  const float* W2_1 = (const float*)d_in[9];
  const float* b2   = (const float*)d_in[10];
  const float* W3_0 = (const float*)d_in[11];
  const float* W3_1 = (const float*)d_in[12];
  const float* b3   = (const float*)d_in[13];
  const float* g3   = (const float*)d_in[14];
  const float* be3  = (const float*)d_in[15];
  const float* W4_0 = (const float*)d_in[16];
  const float* W4_1 = (const float*)d_in[17];
  const float* b4   = (const float*)d_in[18];
  float* out = (float*)d_out;

  char* p = (char*)d_ws;
  size_t off = 0;
  auto alloc = [&](size_t b) -> void* {
    void* r = p + off;
    off += (b + 255) & ~(size_t)255;
    return r;
  };
  float* s_sum  = (float*)alloc(4);
  float* stats0 = (float*)alloc(2 * 64 * 4);
  float* stats1 = (float*)alloc(2 * 64 * 4);
  int*   degi   = (int*)alloc(sizeof(int) * NNODES);
  size_t zero_bytes = off;                       // region that must start at 0
  float* dinv    = (float*)alloc(sizeof(float) * NNODES);
  int*   row_ptr = (int*)alloc(sizeof(int) * (NNODES + 1));
  int*   bsum    = (int*)alloc(256 * sizeof(int));
  int*   cursor  = (int*)alloc(sizeof(int) * NNODES);
  int2*  ep      = (int2*)alloc(8ULL * NEDGES);
  float* big1    = (float*)alloc(4ULL * NNODES * FEAT);  // zz1, then h3/agg4
  float* h1      = (float*)alloc(4ULL * NNODES * 64);

  // big0 lives in d_out: xn, then zz2/h2/agg3 — all dead before the final
  // GEMM overwrites out. (out is N x 128 floats = exactly N*FEAT.)
  float* big0 = out;
  float* xn   = big0;
  float* zz2  = big0;                       // N x 32 (after xn is dead)
  float* h2   = big0 + (size_t)NNODES * 32; // N x 16
  float* agg3 = big0 + (size_t)NNODES * 48; // N x 16
  float* zz1  = big1;                       // N x 128 = [xw0 | xw1]
  float* h3   = big1;                       // N x 64 (after zz1 is dead)
  float* agg4 = big1 + (size_t)NNODES * 64; // N x 64

  hipMemsetAsync(d_ws, 0, zero_bytes, stream);

  int n4 = NNODES * FEAT / 4;
  sum_kernel<<<2048, 256, 0, stream>>>(x, s_sum, n4);
  noisy_kernel<<<(n4 + 255) / 256, 256, 0, stream>>>(x, noise, s_sum, xn, n4);
  degree_kernel<<<(NEDGES + 255) / 256, 256, 0, stream>>>(ei, degi, NEDGES);
  dinv_kernel<<<(NNODES + 255) / 256, 256, 0, stream>>>(degi, dinv, NNODES);
  scan1_kernel<<<(NNODES + 1023) / 1024, 1024, 0, stream>>>(degi, row_ptr, bsum, NNODES);
  scan2_kernel<<<1, 256, 0, stream>>>(bsum, (NNODES + 1023) / 1024);
  scan3_kernel<<<(NNODES + 256) / 256, 256, 0, stream>>>(row_ptr, bsum, cursor, NNODES);
  csr_fill_kernel<<<(NEDGES + 255) / 256, 256, 0, stream>>>(ei, dinv, cursor, ep, NEDGES);

  // Layer 1: 128 -> 64 (transform-first), BN + ReLU
  gemm_kernel<128, 128, false, false><<<(NNODES + 31) / 32, 256, 0, stream>>>(
      xn, nullptr, W1_0, W1_1, nullptr, zz1, NNODES);
  spmm_kernel<64, true><<<(NNODES + 3) / 4, 256, 0, stream>>>(
      row_ptr, ep, zz1, 128, 64, b1, h1, NNODES);
  bn_stats_kernel<64><<<256, 256, 0, stream>>>(h1, stats0, NNODES);
  bn_apply_kernel<64><<<(NNODES * 64 + 255) / 256, 256, 0, stream>>>(h1, stats0, g1, be1, NNODES);

  // Layer 2: 64 -> 16 (transform-first)
  gemm_kernel<64, 32, false, false><<<(NNODES + 127) / 128, 256, 0, stream>>>(
      h1, nullptr, W2_0, W2_1, nullptr, zz2, NNODES);
  spmm_kernel<16, true><<<(NNODES + 15) / 16, 256, 0, stream>>>(
      row_ptr, ep, zz2, 32, 16, b2, h2, NNODES);

  // Layer 3: 16 -> 64 (aggregate-first), BN + ReLU
  spmm_kernel<16, false><<<(NNODES + 15) / 16, 256, 0, stream>>>(
      row_ptr, ep, h2, 16, 0, nullptr, agg3, NNODES);
  gemm_kernel<32, 64, true, true><<<(NNODES + 63) / 64, 256, 0, stream>>>(
      h2, agg3, W3_0, W3_1, b3, h3, NNODES);
  bn_stats_kernel<64><<<256, 256, 0, stream>>>(h3, stats1, NNODES);
  bn_apply_kernel<64><<<(NNODES * 64 + 255) / 256, 256, 0, stream>>>(h3, stats1, g3, be3, NNODES);

  // Layer 4: 64 -> 128 (aggregate-first)
  spmm_kernel<64, false><<<(NNODES + 3) / 4, 256, 0, stream>>>(
      row_ptr, ep, h3, 64, 0, nullptr, agg4, NNODES);
  gemm_kernel<128, 128, true, true><<<(NNODES + 31) / 32, 256, 0, stream>>>(
      h3, agg4, W4_0, W4_1, b4, out, NNODES);
}

// Round 4
// 736.842 us; speedup vs baseline: 1.0254x; 1.0254x over previous
//
#include <hip/hip_runtime.h>

#define NNODES 50000
#define NEDGES 1600000
#define FEAT   128
#define EPSV   1e-5f

__device__ __forceinline__ float4 f4fma(float w, float4 r, float4 a) {
  a.x = fmaf(w, r.x, a.x); a.y = fmaf(w, r.y, a.y);
  a.z = fmaf(w, r.z, a.z); a.w = fmaf(w, r.w, a.w);
  return a;
}
__device__ __forceinline__ float4 f4bnrelu(float4 r, float4 s, float4 t) {
  float4 o;
  o.x = fmaxf(fmaf(r.x, s.x, t.x), 0.f);
  o.y = fmaxf(fmaf(r.y, s.y, t.y), 0.f);
  o.z = fmaxf(fmaf(r.z, s.z, t.z), 0.f);
  o.w = fmaxf(fmaf(r.w, s.w, t.w), 0.f);
  return o;
}

// ---------------- sum of all x (for mean) ----------------
__global__ __launch_bounds__(256) void sum_kernel(const float* __restrict__ x,
                                                  float* __restrict__ out, int n4) {
  const float4* x4 = (const float4*)x;
  float s = 0.f;
  for (int i = blockIdx.x * blockDim.x + threadIdx.x; i < n4; i += gridDim.x * blockDim.x) {
    float4 v = x4[i];
    s += v.x + v.y + v.z + v.w;
  }
  for (int off = 32; off > 0; off >>= 1) s += __shfl_down(s, off);
  __shared__ float ls[4];
  int wid = threadIdx.x >> 6;
  if ((threadIdx.x & 63) == 0) ls[wid] = s;
  __syncthreads();
  if (threadIdx.x == 0) atomicAdd(out, ls[0] + ls[1] + ls[2] + ls[3]);
}

// ---------------- degree over dst ----------------
__global__ __launch_bounds__(256) void degree_kernel(const int* __restrict__ ei,
                                                     int* __restrict__ degi, int ne) {
  int e = blockIdx.x * blockDim.x + threadIdx.x;
  if (e < ne) atomicAdd(&degi[ei[NEDGES + e]], 1);
}

__global__ __launch_bounds__(256) void dinv_kernel(const int* __restrict__ degi,
                                                   float* __restrict__ dinv, int n) {
  int i = blockIdx.x * blockDim.x + threadIdx.x;
  if (i < n) dinv[i] = (degi[i] > 0) ? rsqrtf((float)degi[i]) : 0.f;
}

// ---------------- exclusive scan (3-kernel, N=50000) ----------------
__global__ __launch_bounds__(1024) void scan1_kernel(const int* __restrict__ cnt,
                                                     int* __restrict__ exc,
                                                     int* __restrict__ bsum, int n) {
  __shared__ int s[1024];
  int tid = threadIdx.x;
  int i = blockIdx.x * 1024 + tid;
  int v = (i < n) ? cnt[i] : 0;
  int val = v;
  s[tid] = v;
  __syncthreads();
  for (int off = 1; off < 1024; off <<= 1) {
    int t = (tid >= off) ? s[tid - off] : 0;
    __syncthreads();
    val += t;
    s[tid] = val;
    __syncthreads();
  }
  if (i < n) exc[i] = val - v;
  if (tid == 1023) bsum[blockIdx.x] = val;
}

__global__ __launch_bounds__(256) void scan2_kernel(int* __restrict__ bsum, int nb) {
  __shared__ int s[256];
  int tid = threadIdx.x;
  int v = (tid < nb) ? bsum[tid] : 0;
  int val = v;
  s[tid] = v;
  __syncthreads();
  for (int off = 1; off < 256; off <<= 1) {
    int t = (tid >= off) ? s[tid - off] : 0;
    __syncthreads();
    val += t;
    s[tid] = val;
    __syncthreads();
  }
  if (tid < nb) bsum[tid] = val - v;
}

__global__ __launch_bounds__(256) void scan3_kernel(int* __restrict__ row_ptr,
                                                    const int* __restrict__ bsum,
                                                    int* __restrict__ cursor, int n) {
  int i = blockIdx.x * blockDim.x + threadIdx.x;
  if (i < n) {
    int v = row_ptr[i] + bsum[i >> 10];
    row_ptr[i] = v;
    cursor[i] = v;
  } else if (i == n) {
    row_ptr[n] = NEDGES;
  }
}

// ---------------- CSR fill: ep[pos] = (src, w_e) ----------------
__global__ __launch_bounds__(256) void csr_fill_kernel(const int* __restrict__ ei,
                                                       const float* __restrict__ dinv,
                                                       int* __restrict__ cursor,
                                                       int2* __restrict__ ep, int ne) {
  int e = blockIdx.x * blockDim.x + threadIdx.x;
  if (e >= ne) return;
  int s = ei[e];
  int d = ei[NEDGES + e];
  float w = dinv[s] * dinv[d];
  int pos = atomicAdd(&cursor[d], 1);
  ep[pos] = make_int2(s, __float_as_int(w));
}

// ---------------- CSR SpMM with optional BN-in (on gathered rows) and stats-out
// out[node][f] = (ADD ? mat[node*S+f] + bias[f] : 0) - sum_e w_e * g(mat[src*S+OFF+f])
// where g = BN+ReLU (from stats_in/gin/bein) when BNIN else identity.
template <int F, int S, int OFF, bool ADD, bool STATS, bool BNIN>
__global__ __launch_bounds__(256) void spmm_kernel(
    const int* __restrict__ row_ptr, const int2* __restrict__ ep,
    const float* __restrict__ mat, const float* __restrict__ bias,
    const float* __restrict__ stats_in, const float* __restrict__ gin,
    const float* __restrict__ bein, float* __restrict__ stats_out,
    float* __restrict__ out, int n) {
  constexpr int LPN = F / 4;          // lanes per node
  constexpr int NPB = 256 / LPN;      // nodes per block
  __shared__ float sst[STATS ? 2 * F : 1];
  if (STATS) {
    if (threadIdx.x < 2 * F) sst[threadIdx.x] = 0.f;
    __syncthreads();
  }
  const int lane = threadIdx.x & (LPN - 1);
  const int g = threadIdx.x / LPN;
  const int node = blockIdx.x * NPB + g;
  const int f0 = lane * 4;
  float4 scl = make_float4(0.f, 0.f, 0.f, 0.f), sht = scl;
  if (BNIN) {
    const float inv_n = 1.0f / (float)n;
    float4 su = *(const float4*)&stats_in[f0];
    float4 sq = *(const float4*)&stats_in[F + f0];
    float4 gg = *(const float4*)&gin[f0];
    float4 bb = *(const float4*)&bein[f0];
    float mu;
    mu = su.x * inv_n; scl.x = gg.x * rsqrtf(sq.x * inv_n - mu * mu + EPSV); sht.x = bb.x - mu * scl.x;
    mu = su.y * inv_n; scl.y = gg.y * rsqrtf(sq.y * inv_n - mu * mu + EPSV); sht.y = bb.y - mu * scl.y;
    mu = su.z * inv_n; scl.z = gg.z * rsqrtf(sq.z * inv_n - mu * mu + EPSV); sht.z = bb.z - mu * scl.z;
    mu = su.w * inv_n; scl.w = gg.w * rsqrtf(sq.w * inv_n - mu * mu + EPSV); sht.w = bb.w - mu * scl.w;
  }
  if (node < n) {
    const float* mb = mat + OFF + f0;
    int e = row_ptr[node];
    const int end = row_ptr[node + 1];
    float4 a0 = make_float4(0.f, 0.f, 0.f, 0.f), a1 = a0, a2 = a0, a3 = a0;
    for (; e + 3 < end; e += 4) {
      int2 s0 = ep[e], s1 = ep[e + 1], s2 = ep[e + 2], s3 = ep[e + 3];
      float4 r0 = *(const float4*)(mb + (size_t)s0.x * S);
      float4 r1 = *(const float4*)(mb + (size_t)s1.x * S);
      float4 r2 = *(const float4*)(mb + (size_t)s2.x * S);
      float4 r3 = *(const float4*)(mb + (size_t)s3.x * S);
      if (BNIN) {
        r0 = f4bnrelu(r0, scl, sht); r1 = f4bnrelu(r1, scl, sht);
        r2 = f4bnrelu(r2, scl, sht); r3 = f4bnrelu(r3, scl, sht);
      }
      a0 = f4fma(__int_as_float(s0.y), r0, a0);
      a1 = f4fma(__int_as_float(s1.y), r1, a1);
      a2 = f4fma(__int_as_float(s2.y), r2, a2);
      a3 = f4fma(__int_as_float(s3.y), r3, a3);
    }
    for (; e < end; ++e) {
      int2 s0 = ep[e];
      float4 r0 = *(const float4*)(mb + (size_t)s0.x * S);
      if (BNIN) r0 = f4bnrelu(r0, scl, sht);
      a0 = f4fma(__int_as_float(s0.y), r0, a0);
    }
    float4 o;
    o.x = (a0.x + a1.x) + (a2.x + a3.x);
    o.y = (a0.y + a1.y) + (a2.y + a3.y);
    o.z = (a0.z + a1.z) + (a2.z + a3.z);
    o.w = (a0.w + a1.w) + (a2.w + a3.w);
    if (ADD) {
      float4 base = *(const float4*)&mat[(size_t)node * S + f0];
      float4 b4 = *(const float4*)&bias[f0];
      o.x = base.x + b4.x - o.x; o.y = base.y + b4.y - o.y;
      o.z = base.z + b4.z - o.z; o.w = base.w + b4.w - o.w;
    } else {
      o.x = -o.x; o.y = -o.y; o.z = -o.z; o.w = -o.w;
    }
    *(float4*)&out[(size_t)node * F + f0] = o;
    if (STATS) {
      atomicAdd(&sst[f0 + 0], o.x); atomicAdd(&sst[F + f0 + 0], o.x * o.x);
      atomicAdd(&sst[f0 + 1], o.y); atomicAdd(&sst[F + f0 + 1], o.y * o.y);
      atomicAdd(&sst[f0 + 2], o.z); atomicAdd(&sst[F + f0 + 2], o.z * o.z);
      atomicAdd(&sst[f0 + 3], o.w); atomicAdd(&sst[F + f0 + 3], o.w * o.w);
    }
  }
  if (STATS) {
    __syncthreads();
    if (threadIdx.x < 2 * F) atomicAdd(&stats_out[threadIdx.x], sst[threadIdx.x]);
  }
}

// ---------------- dense GEMM column-block ----------------
// Computes out[:, col0:col0+NB] (out row stride NT) of the logical product
// [A | ...] @ Wcat where:
//  ROWCAT: Wcat[k,j] = k<K/2 ? W0[k*NT+j] : W1[(k-K/2)*NT+j]; A rows = [A1 | A2] (K/2 each)
// !ROWCAT: Wcat[k,j] = j<NT/2 ? W0[k*(NT/2)+j] : W1[k*(NT/2)+j-NT/2]; A = A1 (K cols)
// BNIN: BN+ReLU applied to A1 elements (feature dim = ROWCAT ? K/2 : K).
// NOISE: A1 := A1 + noise*mean (mean = sumv/(N*FEAT)).
// STATS: per-feature sum/sumsq of out accumulated into stats_out[2*NB] (requires NB==NT).
template <int K, int NB, int NT, bool ROWCAT, bool BIAS, bool BNIN, bool STATS, bool NOISE>
__global__ __launch_bounds__(256) void gemm_kernel(
    const float* __restrict__ A1, const float* __restrict__ A2,
    const float* __restrict__ W0, const float* __restrict__ W1,
    const float* __restrict__ bias, int col0,
    const float* __restrict__ noise, const float* __restrict__ sumv,
    const float* __restrict__ stats_in, const float* __restrict__ gin,
    const float* __restrict__ bein, float* __restrict__ stats_out,
    float* __restrict__ out, int n) {
  constexpr int TC  = NB / 4;
  constexpr int RG  = 256 / TC;
  constexpr int RPT = 4;
  constexpr int RPB = RG * RPT;
  constexpr int AP  = (K == 128) ? K : (K + 1);
  constexpr int KB  = ROWCAT ? K / 2 : K;
  __shared__ float wl[K * NB];
  __shared__ float al[RPB * AP];
  __shared__ float sarr[BNIN ? KB : 1];
  __shared__ float tarr[BNIN ? KB : 1];
  __shared__ float sst[STATS ? 2 * NB : 1];
  const int tid = threadIdx.x;
  if (STATS && tid < 2 * NB) sst[tid] = 0.f;
  if (BNIN) {
    const float inv_n = 1.0f / (float)n;
    for (int f = tid; f < KB; f += 256) {
      float mu = stats_in[f] * inv_n;
      float var = stats_in[KB + f] * inv_n - mu * mu;
      float s = gin[f] * rsqrtf(var + EPSV);
      sarr[f] = s;
      tarr[f] = bein[f] - mu * s;
    }
    __syncthreads();
  }
  float mean = 0.f;
  if (NOISE) mean = sumv[0] * (1.0f / (float)(NNODES * FEAT));

  for (int i = tid; i < K * NB; i += 256) {
    int k = i / NB, j = i - k * NB;
    int jg = col0 + j;
    float v;
    if (ROWCAT) v = (k < K / 2) ? W0[k * NT + jg] : W1[(k - K / 2) * NT + jg];
    else        v = (jg < NT / 2) ? W0[k * (NT / 2) + jg] : W1[k * (NT / 2) + (jg - NT / 2)];
    wl[i] = v;
  }
  const int row0 = blockIdx.x * RPB;
  for (int i = tid; i < RPB * K; i += 256) {
    int r = i / K, k = i - r * K;
    int gr = row0 + r;
    float v = 0.f;
    if (gr < n) {
      if (ROWCAT) {
        if (k < K / 2) {
          v = A1[(size_t)gr * (K / 2) + k];
          if (BNIN) v = fmaxf(fmaf(v, sarr[k], tarr[k]), 0.f);
        } else {
          v = A2[(size_t)gr * (K / 2) + (k - K / 2)];
        }
      } else {
        v = A1[(size_t)gr * K + k];
        if (BNIN) v = fmaxf(fmaf(v, sarr[k], tarr[k]), 0.f);
        if (NOISE) v = fmaf(noise[(size_t)gr * K + k], mean, v);
      }
    }
    al[r * AP + k] = v;
  }
  __syncthreads();

  const int jt = (tid % TC) * 4;
  const int rbase = (tid / TC) * RPT;
  float acc[RPT][4] = {};
#pragma unroll 4
  for (int k = 0; k < K; ++k) {
    float4 w4 = *(const float4*)&wl[k * NB + jt];
#pragma unroll
    for (int rr = 0; rr < RPT; ++rr) {
      float a = al[(rbase + rr) * AP + k];
      acc[rr][0] = fmaf(a, w4.x, acc[rr][0]);
      acc[rr][1] = fmaf(a, w4.y, acc[rr][1]);
      acc[rr][2] = fmaf(a, w4.z, acc[rr][2]);
      acc[rr][3] = fmaf(a, w4.w, acc[rr][3]);
    }
  }
  float4 b4 = make_float4(0.f, 0.f, 0.f, 0.f);
  if (BIAS) b4 = *(const float4*)&bias[col0 + jt];
  float sl[4] = {}, ql[4] = {};
#pragma unroll
  for (int rr = 0; rr < RPT; ++rr) {
    int gr = row0 + rbase + rr;
    if (gr < n) {
      float o0 = acc[rr][0] + b4.x, o1 = acc[rr][1] + b4.y;
      float o2 = acc[rr][2] + b4.z, o3 = acc[rr][3] + b4.w;
      float4 o = make_float4(o0, o1, o2, o3);
      *(float4*)&out[(size_t)gr * NT + col0 + jt] = o;
      if (STATS) {
        sl[0] += o0; ql[0] += o0 * o0; sl[1] += o1; ql[1] += o1 * o1;
        sl[2] += o2; ql[2] += o2 * o2; sl[3] += o3; ql[3] += o3 * o3;
      }
    }
  }
  if (STATS) {
#pragma unroll
    for (int j = 0; j < 4; ++j) {
      atomicAdd(&sst[jt + j], sl[j]);
      atomicAdd(&sst[NB + jt + j], ql[j]);
    }
    __syncthreads();
    if (tid < 2 * NB) atomicAdd(&stats_out[tid], sst[tid]);
  }
}

extern "C" void kernel_launch(void* const* d_in, const int* in_sizes, int n_in,
                              void* d_out, int out_size, void* d_ws, size_t ws_size,
                              hipStream_t stream) {
  const float* x     = (const float*)d_in[0];
  const float* noise = (const float*)d_in[1];
  const int*   ei    = (const int*)d_in[2];   // int32 per harness convention
  const float* W1_0 = (const float*)d_in[3];
  const float* W1_1 = (const float*)d_in[4];
  const float* b1   = (const float*)d_in[5];
  const float* g1   = (const float*)d_in[6];
  const float* be1  = (const float*)d_in[7];
  const float* W2_0 = (const float*)d_in[8];
  const float* W2_1 = (const float*)d_in[9];
  const float* b2   = (const float*)d_in[10];
  const float* W3_0 = (const float*)d_in[11];
  const float* W3_1 = (const float*)d_in[12];
  const float* b3   = (const float*)d_in[13];
  const float* g3   = (const float*)d_in[14];
  const float* be3  = (const float*)d_in[15];
  const float* W4_0 = (const float*)d_in[16];
  const float* W4_1 = (const float*)d_in[17];
  const float* b4   = (const float*)d_in[18];
  float* out = (float*)d_out;

  char* p = (char*)d_ws;
  size_t off = 0;
  auto alloc = [&](size_t b) -> void* {
    void* r = p + off;
    off += (b + 255) & ~(size_t)255;
    return r;
  };
  float* s_sum  = (float*)alloc(4);
  float* stats0 = (float*)alloc(2 * 64 * 4);
  float* stats1 = (float*)alloc(2 * 64 * 4);
  int*   degi   = (int*)alloc(sizeof(int) * NNODES);
  size_t zero_bytes = off;                       // region that must start at 0
  float* dinv    = (float*)alloc(sizeof(float) * NNODES);
  int*   row_ptr = (int*)alloc(sizeof(int) * (NNODES + 1));
  int*   bsum    = (int*)alloc(256 * sizeof(int));
  int*   cursor  = (int*)alloc(sizeof(int) * NNODES);
  int2*  ep      = (int2*)alloc(8ULL * NEDGES);
  float* big1    = (float*)alloc(4ULL * NNODES * FEAT);  // zz1, then h3/agg4
  float* h1      = (float*)alloc(4ULL * NNODES * 64);

  // big0 lives in d_out: zz2/h2/agg3 are all dead before gemm4 writes out.
  float* big0 = out;
  float* zz2  = big0;                       // N x 32
  float* h2   = big0 + (size_t)NNODES * 32; // N x 16
  float* agg3 = big0 + (size_t)NNODES * 48; // N x 16
  float* zz1  = big1;                       // N x 128 = [xw0 | xw1]
  float* h3   = big1;                       // N x 64 (after zz1 dead)
  float* agg4 = big1 + (size_t)NNODES * 64; // N x 64

  hipMemsetAsync(d_ws, 0, zero_bytes, stream);

  int n4 = NNODES * FEAT / 4;
  sum_kernel<<<2048, 256, 0, stream>>>(x, s_sum, n4);
  degree_kernel<<<(NEDGES + 255) / 256, 256, 0, stream>>>(ei, degi, NEDGES);
  dinv_kernel<<<(NNODES + 255) / 256, 256, 0, stream>>>(degi, dinv, NNODES);
  scan1_kernel<<<(NNODES + 1023) / 1024, 1024, 0, stream>>>(degi, row_ptr, bsum, NNODES);
  scan2_kernel<<<1, 256, 0, stream>>>(bsum, (NNODES + 1023) / 1024);
  scan3_kernel<<<(NNODES + 256) / 256, 256, 0, stream>>>(row_ptr, bsum, cursor, NNODES);
  csr_fill_kernel<<<(NEDGES + 255) / 256, 256, 0, stream>>>(ei, dinv, cursor, ep, NEDGES);

  // Layer 1: zz1 = [xn@W1_0 | xn@W1_1] with fused noise; h1 + stats0 via spmm
  gemm_kernel<128, 64, 128, false, false, false, false, true>
      <<<(NNODES + 63) / 64, 256, 0, stream>>>(x, nullptr, W1_0, W1_1, nullptr, 0,
          noise, s_sum, nullptr, nullptr, nullptr, nullptr, zz1, NNODES);
  gemm_kernel<128, 64, 128, false, false, false, false, true>
      <<<(NNODES + 63) / 64, 256, 0, stream>>>(x, nullptr, W1_0, W1_1, nullptr, 64,
          noise, s_sum, nullptr, nullptr, nullptr, nullptr, zz1, NNODES);
  spmm_kernel<64, 128, 64, true, true, false><<<(NNODES + 15) / 16, 256, 0, stream>>>(
      row_ptr, ep, zz1, b1, nullptr, nullptr, nullptr, stats0, h1, NNODES);

  // Layer 2: zz2 = [bn1(h1)@W2_0 | bn1(h1)@W2_1]; h2 via spmm
  gemm_kernel<64, 32, 32, false, false, true, false, false>
      <<<(NNODES + 127) / 128, 256, 0, stream>>>(h1, nullptr, W2_0, W2_1, nullptr, 0,
          nullptr, nullptr, stats0, g1, be1, nullptr, zz2, NNODES);
  spmm_kernel<16, 32, 16, true, false, false><<<(NNODES + 63) / 64, 256, 0, stream>>>(
      row_ptr, ep, zz2, b2, nullptr, nullptr, nullptr, nullptr, h2, NNODES);

  // Layer 3: agg3 = -A h2; h3 = h2@W3_0 + agg3@W3_1 + b3 with stats1
  spmm_kernel<16, 16, 0, false, false, false><<<(NNODES + 63) / 64, 256, 0, stream>>>(
      row_ptr, ep, h2, nullptr, nullptr, nullptr, nullptr, nullptr, agg3, NNODES);
  gemm_kernel<32, 64, 64, true, true, false, true, false>
      <<<(NNODES + 63) / 64, 256, 0, stream>>>(h2, agg3, W3_0, W3_1, b3, 0,
          nullptr, nullptr, nullptr, nullptr, nullptr, stats1, h3, NNODES);

  // Layer 4: agg4 = -A bn3(h3); out = bn3(h3)@W4_0 + agg4@W4_1 + b4
  spmm_kernel<64, 64, 0, false, false, true><<<(NNODES + 15) / 16, 256, 0, stream>>>(
      row_ptr, ep, h3, nullptr, stats1, g3, be3, nullptr, agg4, NNODES);
  gemm_kernel<128, 64, 128, true, true, true, false, false>
      <<<(NNODES + 63) / 64, 256, 0, stream>>>(h3, agg4, W4_0, W4_1, b4, 0,
          nullptr, nullptr, stats1, g3, be3, nullptr, out, NNODES);
  gemm_kernel<128, 64, 128, true, true, true, false, false>
      <<<(NNODES + 63) / 64, 256, 0, stream>>>(h3, agg4, W4_0, W4_1, b4, 64,
          nullptr, nullptr, stats1, g3, be3, nullptr, out, NNODES);
}

// Round 7
// 683.477 us; speedup vs baseline: 1.1055x; 1.0781x over previous
//
#include <hip/hip_runtime.h>

#define NNODES 50000
#define NEDGES 1600000
#define FEAT   128
#define EPSV   1e-5f

typedef _Float16 h8 __attribute__((ext_vector_type(8)));
typedef _Float16 h4 __attribute__((ext_vector_type(4)));

__device__ __forceinline__ float4 f4fma(float s, float4 w, float4 a) {
  a.x = fmaf(s, w.x, a.x); a.y = fmaf(s, w.y, a.y);
  a.z = fmaf(s, w.z, a.z); a.w = fmaf(s, w.w, a.w);
  return a;
}

// ---------------- sum of all x (for mean) ----------------
__global__ __launch_bounds__(256) void sum_kernel(const float* __restrict__ x,
                                                  float* __restrict__ out, int n4) {
  const float4* x4 = (const float4*)x;
  float s = 0.f;
  for (int i = blockIdx.x * blockDim.x + threadIdx.x; i < n4; i += gridDim.x * blockDim.x) {
    float4 v = x4[i];
    s += v.x + v.y + v.z + v.w;
  }
  for (int off = 32; off > 0; off >>= 1) s += __shfl_down(s, off);
  __shared__ float ls[4];
  int wid = threadIdx.x >> 6;
  if ((threadIdx.x & 63) == 0) ls[wid] = s;
  __syncthreads();
  if (threadIdx.x == 0) atomicAdd(out, ls[0] + ls[1] + ls[2] + ls[3]);
}

// ---------------- degree over dst ----------------
__global__ __launch_bounds__(256) void degree_kernel(const int* __restrict__ ei,
                                                     int* __restrict__ degi, int ne) {
  int e = blockIdx.x * blockDim.x + threadIdx.x;
  if (e < ne) atomicAdd(&degi[ei[NEDGES + e]], 1);
}

__global__ __launch_bounds__(256) void dinv_kernel(const int* __restrict__ degi,
                                                   float* __restrict__ dinv, int n) {
  int i = blockIdx.x * blockDim.x + threadIdx.x;
  if (i < n) dinv[i] = (degi[i] > 0) ? rsqrtf((float)degi[i]) : 0.f;
}

// ---------------- exclusive scan (3-kernel, N=50000) ----------------
__global__ __launch_bounds__(1024) void scan1_kernel(const int* __restrict__ cnt,
                                                     int* __restrict__ exc,
                                                     int* __restrict__ bsum, int n) {
  __shared__ int s[1024];
  int tid = threadIdx.x;
  int i = blockIdx.x * 1024 + tid;
  int v = (i < n) ? cnt[i] : 0;
  int val = v;
  s[tid] = v;
  __syncthreads();
  for (int off = 1; off < 1024; off <<= 1) {
    int t = (tid >= off) ? s[tid - off] : 0;
    __syncthreads();
    val += t;
    s[tid] = val;
    __syncthreads();
  }
  if (i < n) exc[i] = val - v;
  if (tid == 1023) bsum[blockIdx.x] = val;
}

__global__ __launch_bounds__(256) void scan2_kernel(int* __restrict__ bsum, int nb) {
  __shared__ int s[256];
  int tid = threadIdx.x;
  int v = (tid < nb) ? bsum[tid] : 0;
  int val = v;
  s[tid] = v;
  __syncthreads();
  for (int off = 1; off < 256; off <<= 1) {
    int t = (tid >= off) ? s[tid - off] : 0;
    __syncthreads();
    val += t;
    s[tid] = val;
    __syncthreads();
  }
  if (tid < nb) bsum[tid] = val - v;
}

__global__ __launch_bounds__(256) void scan3_kernel(int* __restrict__ row_ptr,
                                                    const int* __restrict__ bsum,
                                                    int* __restrict__ cursor, int n) {
  int i = blockIdx.x * blockDim.x + threadIdx.x;
  if (i < n) {
    int v = row_ptr[i] + bsum[i >> 10];
    row_ptr[i] = v;
    cursor[i] = v;
  } else if (i == n) {
    row_ptr[n] = NEDGES;
  }
}

// ---------------- CSR fill: ep[pos] = (src, w_e) ----------------
__global__ __launch_bounds__(256) void csr_fill_kernel(const int* __restrict__ ei,
                                                       const float* __restrict__ dinv,
                                                       int* __restrict__ cursor,
                                                       int2* __restrict__ ep, int ne) {
  int e = blockIdx.x * blockDim.x + threadIdx.x;
  if (e >= ne) return;
  int s = ei[e];
  int d = ei[NEDGES + e];
  float w = dinv[s] * dinv[d];
  int pos = atomicAdd(&cursor[d], 1);
  ep[pos] = make_int2(s, __float_as_int(w));
}

// ---------------- CSR SpMM, fp16 gathered rows, 1 node/wave edge-parallel ----
// out[node][:] = (ADD ? addL[node][:] + bias : 0) - sum_e w_e * g(gsrc[src][:])
// g = BN+ReLU when BNIN. Lane-group: LPE = F/8 lanes per edge, each lane owns
// 8 features (16B fp16). EPC = 64/LPE edges per chunk, unroll 2 -> 2*EPC rows
// in flight per wave. Uniform loop bound per wave (divergence <= 1 chunk).
template <int F, bool ADD, bool STATS, bool BNIN, bool OUTH>
__global__ __launch_bounds__(256) void spmm_kernel(
    const int* __restrict__ row_ptr, const int2* __restrict__ ep,
    const _Float16* __restrict__ gsrc, const float* __restrict__ addL,
    const float* __restrict__ bias,
    const float* __restrict__ stats_in, const float* __restrict__ gin,
    const float* __restrict__ bein, float* __restrict__ stats_out,
    void* __restrict__ outv, int n) {
  constexpr int LPE = F / 8;     // lanes per edge
  constexpr int EPC = 64 / LPE;  // edges per chunk
  constexpr int LG  = (LPE == 2) ? 1 : 3;
  __shared__ float sst[STATS ? 2 * F : 1];
  const int tid = threadIdx.x;
  if (STATS) {
    if (tid < 2 * F) sst[tid] = 0.f;
    __syncthreads();
  }
  const int lane = tid & 63;
  const int wv = tid >> 6;
  const int sub = lane & (LPE - 1);
  const int g = lane >> LG;
  const int f0 = sub * 8;
  float scl[8], sht[8];
  if (BNIN) {
    const float inv_n = 1.0f / (float)n;
#pragma unroll
    for (int j = 0; j < 8; ++j) {
      int f = f0 + j;
      float mu = stats_in[f] * inv_n;
      float var = stats_in[F + f] * inv_n - mu * mu;
      float s = gin[f] * rsqrtf(var + EPSV);
      scl[j] = s;
      sht[j] = bein[f] - mu * s;
    }
  }
  for (int node = blockIdx.x * 4 + wv; node < n; node += gridDim.x * 4) {
    float acc[8] = {};
    const int beg = row_ptr[node], end = row_ptr[node + 1];
    int e = beg + g;
    while (e < end) {
      int2 s0 = ep[e];
      bool p1 = (e + EPC) < end;
      int2 s1 = ep[p1 ? e + EPC : e];
      float w0 = __int_as_float(s0.y);
      float w1 = p1 ? __int_as_float(s1.y) : 0.f;
      h8 r0 = *(const h8*)(gsrc + (size_t)s0.x * F + f0);
      h8 r1 = *(const h8*)(gsrc + (size_t)s1.x * F + f0);
#pragma unroll
      for (int j = 0; j < 8; ++j) {
        float v0 = (float)r0[j], v1 = (float)r1[j];
        if (BNIN) {
          v0 = fmaxf(fmaf(v0, scl[j], sht[j]), 0.f);
          v1 = fmaxf(fmaf(v1, scl[j], sht[j]), 0.f);
        }
        acc[j] = fmaf(w0, v0, acc[j]);
        acc[j] = fmaf(w1, v1, acc[j]);
      }
      e += 2 * EPC;
    }
#pragma unroll
    for (int m = LPE; m < 64; m <<= 1) {
#pragma unroll
      for (int j = 0; j < 8; ++j) acc[j] += __shfl_xor(acc[j], m);
    }
    if (lane < LPE) {
      float o[8];
      if (ADD) {
        float4 a0 = *(const float4*)&addL[(size_t)node * F + f0];
        float4 a1 = *(const float4*)&addL[(size_t)node * F + f0 + 4];
        float4 b0 = *(const float4*)&bias[f0];
        float4 b1 = *(const float4*)&bias[f0 + 4];
        o[0] = a0.x + b0.x - acc[0]; o[1] = a0.y + b0.y - acc[1];
        o[2] = a0.z + b0.z - acc[2]; o[3] = a0.w + b0.w - acc[3];
        o[4] = a1.x + b1.x - acc[4]; o[5] = a1.y + b1.y - acc[5];
        o[6] = a1.z + b1.z - acc[6]; o[7] = a1.w + b1.w - acc[7];
      } else {
#pragma unroll
        for (int j = 0; j < 8; ++j) o[j] = -acc[j];
      }
      if (OUTH) {
        h8 ho;
#pragma unroll
        for (int j = 0; j < 8; ++j) ho[j] = (_Float16)o[j];
        *(h8*)((_Float16*)outv + (size_t)node * F + f0) = ho;
      } else {
        float* op = (float*)outv + (size_t)node * F + f0;
        *(float4*)op = make_float4(o[0], o[1], o[2], o[3]);
        *(float4*)(op + 4) = make_float4(o[4], o[5], o[6], o[7]);
      }
      if (STATS) {
#pragma unroll
        for (int j = 0; j < 8; ++j) {
          atomicAdd(&sst[f0 + j], o[j]);
          atomicAdd(&sst[F + f0 + j], o[j] * o[j]);
        }
      }
    }
  }
  if (STATS) {
    __syncthreads();
    if (tid < 2 * F) atomicAdd(&stats_out[tid], sst[tid]);
  }
}

// ---------------- dense GEMM column-block ----------------
// out[:, weight cols col0:col0+NB]. Weight layout:
//  ROWCAT: Wcat[k,j] = k<K/2 ? W0[k*wnt+j] : W1[(k-K/2)*wnt+j]; A = [A1 | A2]
// !ROWCAT: Wcat[k,j] = j<wnt/2 ? W0[k*(wnt/2)+j] : W1[k*(wnt/2)+j-wnt/2]; A = A1
// A1 fp16 when A1H. BNIN: BN+ReLU on A1 (feature dim KB). NOISE: A1 += noise*mean.
// OMODE 0: fp32 out at [gr*ostride + ocol0 + jt]; 1: fp16 same; 2: split
// (jt<16 -> fp32 outv stride16, else fp16 out2 stride16). STATS needs NB==full.
template <int K, int NB, bool ROWCAT, bool BIAS, bool BNIN, bool STATS, bool NOISE,
          bool A1H, int OMODE>
__global__ __launch_bounds__(256) void gemm_kernel(
    const void* __restrict__ A1, const float* __restrict__ A2,
    const float* __restrict__ W0, const float* __restrict__ W1,
    const float* __restrict__ bias, int col0, int wnt, int ostride, int ocol0,
    const float* __restrict__ noise, const float* __restrict__ sumv,
    const float* __restrict__ stats_in, const float* __restrict__ gin,
    const float* __restrict__ bein, float* __restrict__ stats_out,
    void* __restrict__ outv, void* __restrict__ out2, int n) {
  constexpr int TC  = NB / 4;
  constexpr int RG  = 256 / TC;
  constexpr int RPT = 4;
  constexpr int RPB = RG * RPT;
  constexpr int AP  = K + 4;
  constexpr int KB  = ROWCAT ? K / 2 : K;
  __shared__ float wl[K * NB];
  __shared__ float al[RPB * AP];
  __shared__ float sarr[BNIN ? KB : 1];
  __shared__ float tarr[BNIN ? KB : 1];
  __shared__ float sst[STATS ? 2 * NB : 1];
  const int tid = threadIdx.x;
  if (STATS && tid < 2 * NB) sst[tid] = 0.f;
  if (BNIN) {
    const float inv_n = 1.0f / (float)n;
    for (int f = tid; f < KB; f += 256) {
      float mu = stats_in[f] * inv_n;
      float var = stats_in[KB + f] * inv_n - mu * mu;
      float s = gin[f] * rsqrtf(var + EPSV);
      sarr[f] = s;
      tarr[f] = bein[f] - mu * s;
    }
  }
  float mean = 0.f;
  if (NOISE) mean = sumv[0] * (1.0f / (float)(NNODES * FEAT));

  for (int i = tid; i < K * NB; i += 256) {
    int k = i / NB, j = i - k * NB;
    int jg = col0 + j;
    float v;
    if (ROWCAT) v = (k < K / 2) ? W0[k * wnt + jg] : W1[(k - K / 2) * wnt + jg];
    else        v = (jg < wnt / 2) ? W0[k * (wnt / 2) + jg] : W1[k * (wnt / 2) + (jg - wnt / 2)];
    wl[i] = v;
  }
  __syncthreads();  // sarr/tarr ready before A staging uses them

  const int row0 = blockIdx.x * RPB;
  for (int i = tid; i < RPB * K; i += 256) {
    int r = i / K, k = i - r * K;
    int gr = row0 + r;
    float v = 0.f;
    if (gr < n) {
      if (ROWCAT) {
        if (k < K / 2) {
          v = A1H ? (float)((const _Float16*)A1)[(size_t)gr * (K / 2) + k]
                  : ((const float*)A1)[(size_t)gr * (K / 2) + k];
          if (BNIN) v = fmaxf(fmaf(v, sarr[k], tarr[k]), 0.f);
        } else {
          v = A2[(size_t)gr * (K / 2) + (k - K / 2)];
        }
      } else {
        v = A1H ? (float)((const _Float16*)A1)[(size_t)gr * K + k]
                : ((const float*)A1)[(size_t)gr * K + k];
        if (BNIN) v = fmaxf(fmaf(v, sarr[k], tarr[k]), 0.f);
        if (NOISE) v = fmaf(noise[(size_t)gr * K + k], mean, v);
      }
    }
    al[r * AP + k] = v;
  }
  __syncthreads();

  const int jt = (tid % TC) * 4;
  const int rbase = (tid / TC) * RPT;
  float4 acc[RPT];
#pragma unroll
  for (int rr = 0; rr < RPT; ++rr) acc[rr] = make_float4(0.f, 0.f, 0.f, 0.f);
  const float4* wl4 = (const float4*)wl;
  const int jt4 = jt >> 2;
#pragma unroll 4
  for (int k0 = 0; k0 < K; k0 += 4) {
    float4 w0 = wl4[(k0 + 0) * TC + jt4];
    float4 w1 = wl4[(k0 + 1) * TC + jt4];
    float4 w2 = wl4[(k0 + 2) * TC + jt4];
    float4 w3 = wl4[(k0 + 3) * TC + jt4];
#pragma unroll
    for (int rr = 0; rr < RPT; ++rr) {
      float4 a = *(const float4*)&al[(rbase + rr) * AP + k0];
      acc[rr] = f4fma(a.x, w0, acc[rr]);
      acc[rr] = f4fma(a.y, w1, acc[rr]);
      acc[rr] = f4fma(a.z, w2, acc[rr]);
      acc[rr] = f4fma(a.w, w3, acc[rr]);
    }
  }
  float4 b4 = make_float4(0.f, 0.f, 0.f, 0.f);
  if (BIAS) b4 = *(const float4*)&bias[col0 + jt];
  float sl[4] = {}, ql[4] = {};
#pragma unroll
  for (int rr = 0; rr < RPT; ++rr) {
    int gr = row0 + rbase + rr;
    if (gr < n) {
      float4 o;
      o.x = acc[rr].x + b4.x; o.y = acc[rr].y + b4.y;
      o.z = acc[rr].z + b4.z; o.w = acc[rr].w + b4.w;
      if (OMODE == 0) {
        *(float4*)((float*)outv + (size_t)gr * ostride + ocol0 + jt) = o;
      } else if (OMODE == 1) {
        h4 ho; ho[0] = (_Float16)o.x; ho[1] = (_Float16)o.y;
        ho[2] = (_Float16)o.z; ho[3] = (_Float16)o.w;
        *(h4*)((_Float16*)outv + (size_t)gr * ostride + ocol0 + jt) = ho;
      } else {
        if (jt < 16) {
          *(float4*)((float*)outv + (size_t)gr * 16 + jt) = o;
        } else {
          h4 ho; ho[0] = (_Float16)o.x; ho[1] = (_Float16)o.y;
          ho[2] = (_Float16)o.z; ho[3] = (_Float16)o.w;
          *(h4*)((_Float16*)out2 + (size_t)gr * 16 + (jt - 16)) = ho;
        }
      }
      if (STATS) {
        sl[0] += o.x; ql[0] += o.x * o.x; sl[1] += o.y; ql[1] += o.y * o.y;
        sl[2] += o.z; ql[2] += o.z * o.z; sl[3] += o.w; ql[3] += o.w * o.w;
      }
    }
  }
  if (STATS) {
#pragma unroll
    for (int j = 0; j < 4; ++j) {
      atomicAdd(&sst[jt + j], sl[j]);
      atomicAdd(&sst[NB + jt + j], ql[j]);
    }
    __syncthreads();
    if (tid < 2 * NB) atomicAdd(&stats_out[tid], sst[tid]);
  }
}

extern "C" void kernel_launch(void* const* d_in, const int* in_sizes, int n_in,
                              void* d_out, int out_size, void* d_ws, size_t ws_size,
                              hipStream_t stream) {
  const float* x     = (const float*)d_in[0];
  const float* noise = (const float*)d_in[1];
  const int*   ei    = (const int*)d_in[2];   // int32 per harness convention
  const float* W1_0 = (const float*)d_in[3];
  const float* W1_1 = (const float*)d_in[4];
  const float* b1   = (const float*)d_in[5];
  const float* g1   = (const float*)d_in[6];
  const float* be1  = (const float*)d_in[7];
  const float* W2_0 = (const float*)d_in[8];
  const float* W2_1 = (const float*)d_in[9];
  const float* b2   = (const float*)d_in[10];
  const float* W3_0 = (const float*)d_in[11];
  const float* W3_1 = (const float*)d_in[12];
  const float* b3   = (const float*)d_in[13];
  const float* g3   = (const float*)d_in[14];
  const float* be3  = (const float*)d_in[15];
  const float* W4_0 = (const float*)d_in[16];
  const float* W4_1 = (const float*)d_in[17];
  const float* b4   = (const float*)d_in[18];
  float* out = (float*)d_out;

  char* p = (char*)d_ws;
  size_t off = 0;
  auto alloc = [&](size_t b) -> void* {
    void* r = p + off;
    off += (b + 255) & ~(size_t)255;
    return r;
  };
  float* s_sum  = (float*)alloc(4);
  float* stats0 = (float*)alloc(2 * 64 * 4);
  float* stats1 = (float*)alloc(2 * 64 * 4);
  int*   degi   = (int*)alloc(sizeof(int) * NNODES);
  size_t zero_bytes = off;                       // region that must start at 0
  float*     dinv    = (float*)alloc(sizeof(float) * NNODES);
  int*       row_ptr = (int*)alloc(sizeof(int) * (NNODES + 1));
  int*       bsum    = (int*)alloc(256 * sizeof(int));
  int*       cursor  = (int*)alloc(sizeof(int) * NNODES);
  int2*      ep      = (int2*)alloc(8ULL * NEDGES);
  float*     zzL     = (float*)alloc(4ULL * NNODES * 64);   // also reused as agg4
  _Float16*  zzRh    = (_Float16*)alloc(2ULL * NNODES * 64);
  float*     h1      = (float*)alloc(4ULL * NNODES * 64);
  _Float16*  zz2Rh   = (_Float16*)alloc(2ULL * NNODES * 16);
  _Float16*  h2      = (_Float16*)alloc(2ULL * NNODES * 16);
  _Float16*  h3h     = (_Float16*)alloc(2ULL * NNODES * 64);
  float*     agg4    = zzL;  // zzL dead after spmm1

  // d_out scratch: zz2L [0, N*16), agg3 [N*16, N*32) — both dead before gemm4.
  float* zz2L = out;
  float* agg3 = out + (size_t)NNODES * 16;

  hipMemsetAsync(d_ws, 0, zero_bytes, stream);

  int n4 = NNODES * FEAT / 4;
  sum_kernel<<<2048, 256, 0, stream>>>(x, s_sum, n4);
  degree_kernel<<<(NEDGES + 255) / 256, 256, 0, stream>>>(ei, degi, NEDGES);
  dinv_kernel<<<(NNODES + 255) / 256, 256, 0, stream>>>(degi, dinv, NNODES);
  scan1_kernel<<<(NNODES + 1023) / 1024, 1024, 0, stream>>>(degi, row_ptr, bsum, NNODES);
  scan2_kernel<<<1, 256, 0, stream>>>(bsum, (NNODES + 1023) / 1024);
  scan3_kernel<<<(NNODES + 256) / 256, 256, 0, stream>>>(row_ptr, bsum, cursor, NNODES);
  csr_fill_kernel<<<(NEDGES + 255) / 256, 256, 0, stream>>>(ei, dinv, cursor, ep, NEDGES);

  // Layer 1: zzL = xn@W1_0 (f32), zzRh = fp16(xn@W1_1); h1 + stats0 via spmm
  gemm_kernel<128, 64, false, false, false, false, true, false, 0>
      <<<(NNODES + 63) / 64, 256, 0, stream>>>(
      x, nullptr, W1_0, W1_1, nullptr, 0, 128, 64, 0,
      noise, s_sum, nullptr, nullptr, nullptr, nullptr, zzL, nullptr, NNODES);
  gemm_kernel<128, 64, false, false, false, false, true, false, 1>
      <<<(NNODES + 63) / 64, 256, 0, stream>>>(
      x, nullptr, W1_0, W1_1, nullptr, 64, 128, 64, 0,
      noise, s_sum, nullptr, nullptr, nullptr, nullptr, zzRh, nullptr, NNODES);
  spmm_kernel<64, true, true, false, false><<<2048, 256, 0, stream>>>(
      row_ptr, ep, zzRh, zzL, b1, nullptr, nullptr, nullptr, stats0, h1, NNODES);

  // Layer 2: zz2L/zz2Rh = bn1(h1)@W2_{0,1} (split f32/f16); h2 (fp16) via spmm
  gemm_kernel<64, 32, false, false, true, false, false, false, 2>
      <<<(NNODES + 127) / 128, 256, 0, stream>>>(
      h1, nullptr, W2_0, W2_1, nullptr, 0, 32, 16, 0,
      nullptr, nullptr, stats0, g1, be1, nullptr, zz2L, zz2Rh, NNODES);
  spmm_kernel<16, true, false, false, true><<<2048, 256, 0, stream>>>(
      row_ptr, ep, zz2Rh, zz2L, b2, nullptr, nullptr, nullptr, nullptr, h2, NNODES);

  // Layer 3: agg3 = -A h2 (f32); h3h = fp16(h2@W3_0 + agg3@W3_1 + b3), stats1
  spmm_kernel<16, false, false, false, false><<<2048, 256, 0, stream>>>(
      row_ptr, ep, h2, nullptr, nullptr, nullptr, nullptr, nullptr, nullptr, agg3, NNODES);
  gemm_kernel<32, 64, true, true, false, true, false, true, 1>
      <<<(NNODES + 63) / 64, 256, 0, stream>>>(
      h2, agg3, W3_0, W3_1, b3, 0, 64, 64, 0,
      nullptr, nullptr, nullptr, nullptr, nullptr, stats1, h3h, nullptr, NNODES);

  // Layer 4: agg4 = -A bn3(h3h) (f32); out = bn3(h3h)@W4_0 + agg4@W4_1 + b4
  spmm_kernel<64, false, false, true, false><<<2048, 256, 0, stream>>>(
      row_ptr, ep, h3h, nullptr, nullptr, stats1, g3, be3, nullptr, agg4, NNODES);
  gemm_kernel<128, 64, true, true, true, false, false, true, 0>
      <<<(NNODES + 63) / 64, 256, 0, stream>>>(
      h3h, agg4, W4_0, W4_1, b4, 0, 128, 128, 0,
      nullptr, nullptr, stats1, g3, be3, nullptr, out, nullptr, NNODES);
  gemm_kernel<128, 64, true, true, true, false, false, true, 0>
      <<<(NNODES + 63) / 64, 256, 0, stream>>>(
      h3h, agg4, W4_0, W4_1, b4, 64, 128, 128, 64,
      nullptr, nullptr, stats1, g3, be3, nullptr, out, nullptr, NNODES);
}